// Round 6
// baseline (6762.949 us; speedup 1.0000x reference)
//
#include <hip/hip_runtime.h>
#include <cstdint>
#include <cstddef>

#define B_   64
#define T_   2048
#define C_   64
#define H_   256
#define G3_  768    // 3*H
#define HOR_ 96

typedef _Float16 h2 __attribute__((ext_vector_type(2)));
typedef _Float16 h4v __attribute__((ext_vector_type(4)));
typedef _Float16 h8 __attribute__((ext_vector_type(8)));
typedef _Float16 f16x8 __attribute__((ext_vector_type(8)));
typedef float f32x4 __attribute__((ext_vector_type(4)));
typedef int i32x4 __attribute__((ext_vector_type(4)));

// ---------------------------------------------------------------------------
// K1: cur[b,t,h] = sum_c x[b,t,c]*snn_w[h,c] + snn_b[h]   (fp32)
// Block (0,0) also zeroes the producer->consumer flags.
// ---------------------------------------------------------------------------
#define K1_TT 128
__global__ __launch_bounds__(256) void k_cur(const float* __restrict__ x,
                                             const float* __restrict__ w,
                                             const float* __restrict__ bias,
                                             float* __restrict__ cur,
                                             int* __restrict__ flags) {
  __shared__ float xs[K1_TT * C_];  // 32 KB
  const int b = blockIdx.x;
  const int t0 = blockIdx.y * K1_TT;
  const int tid = threadIdx.x;

  if (b == 0 && blockIdx.y == 0) {
#pragma unroll
    for (int i = 0; i < 4; i++) flags[tid + i * 256] = 0;
  }

  const float4* xsrc = (const float4*)(x + ((size_t)b * T_ + t0) * C_);
  float4* xdst = (float4*)xs;
#pragma unroll
  for (int i = 0; i < (K1_TT * C_ / 4) / 256; i++)
    xdst[tid + i * 256] = xsrc[tid + i * 256];

  float wr[C_];
  const float4* wp = (const float4*)(w + (size_t)tid * C_);
#pragma unroll
  for (int q = 0; q < C_ / 4; q++) {
    float4 v = wp[q];
    wr[4 * q + 0] = v.x; wr[4 * q + 1] = v.y;
    wr[4 * q + 2] = v.z; wr[4 * q + 3] = v.w;
  }
  const float bb = bias[tid];
  __syncthreads();

  for (int t = 0; t < K1_TT; t++) {
    const float4* xrow = (const float4*)(xs + t * C_);
    float a0 = 0.f, a1 = 0.f;
#pragma unroll
    for (int q = 0; q < C_ / 4; q += 2) {
      float4 v0 = xrow[q];
      float4 v1 = xrow[q + 1];
      a0 += wr[4 * q + 0] * v0.x + wr[4 * q + 1] * v0.y +
            wr[4 * q + 2] * v0.z + wr[4 * q + 3] * v0.w;
      a1 += wr[4 * q + 4] * v1.x + wr[4 * q + 5] * v1.y +
            wr[4 * q + 6] * v1.z + wr[4 * q + 7] * v1.w;
    }
    cur[((size_t)b * T_ + t0 + t) * H_ + tid] = a0 + a1 + bb;
  }
}

// ---------------------------------------------------------------------------
// K2: LIF scan per (b,h). Spikes stored as u8 (exact).
// ---------------------------------------------------------------------------
__global__ __launch_bounds__(64) void k_lif(const float* __restrict__ cur,
                                            unsigned char* __restrict__ spk) {
  const int b = blockIdx.x >> 2;
  const int h = ((blockIdx.x & 3) << 6) + threadIdx.x;
  const float* cp = cur + (size_t)b * T_ * H_ + h;
  unsigned char* sp = spk + (size_t)b * T_ * H_ + h;
  float mem = 0.f;
#pragma unroll 32
  for (int t = 0; t < T_; t++) {
    float c = cp[(size_t)t * H_];
    float reset = (mem > 1.0f) ? 1.0f : 0.0f;  // from previous mem
    mem = 0.9f * mem + c - reset;              // THR = 1
    sp[(size_t)t * H_] = (mem > 1.0f) ? (unsigned char)1 : (unsigned char)0;
  }
}

// ---------------------------------------------------------------------------
// K3+K4 FUSED — 512 threads/block.
// ROUND-6 REWRITE (consumer): rounds 4+5 proved the scan is ISSUE-bound on
// the VALU (LDS-latency and gx-latency pins both exactly neutral; consumer
// VALUBusy ~55% after producer-burst accounting). Fix: batch 16 GRU chains
// per block and move the hh-matvec to the MFMA pipe: per step a 768x256x16
// i8 GEMM = 48 mfma_i32_16x16x64_i8 (24/wave, 8 waves). W lives in VGPRs as
// A-fragments: 96 dwords/thread (half of the old 192 -> no spill at the
// 256-VGPR budget, amdgpu_waves_per_eu(2)). i32 accum == sdot4 bit-exact.
// Fragment layouts validated by this kernel's own producer:
//   A-frag row = lane&15, k = (lane>>4)*KB + e (KB=16 for i8 K=64)
//   D row = (lane>>4)*4 + reg, col = lane&15.
// Tail (sigmoid/tanh) stays fp32, 8 (j,b) pairs/thread -> VALU work per
// batch-step drops 16x. h exchanged as i8 in LDS [b][k] (k-contig = B-frag).
//  blocks 0..3    : GRU consumers, 16 batches each.
//  blocks 4..195  : gx producers — 3 per batch (round-2 512-thr tile).
// ROUND-3 LESSON: stay under the VGPR cliff (est ~215 regs).
// ROUND-2 LESSON: no redundant per-SIMD issue; MFMA adds batch-parallel work.
// ---------------------------------------------------------------------------
#define GM 128
#define GN 128
#define AKP 40   // padded K-chunk stride (halves)
#define CTP 136  // C-transpose row stride (halves)
#define HQP 288  // h_q8 row pad (bytes): 4-way max on b128 frag reads
#define DQ_ (0.0625f / (127.0f * 127.0f))
__global__ __attribute__((amdgpu_flat_work_group_size(512, 512),
                          amdgpu_waves_per_eu(2))) void k_fused(
    const float* __restrict__ x, const unsigned char* __restrict__ spk,
    const float* __restrict__ wih, const float* __restrict__ bih,
    _Float16* __restrict__ gx, const float* __restrict__ whh,
    const float* __restrict__ bhh, const float* __restrict__ head_w,
    const float* __restrict__ head_b, float* __restrict__ out,
    int* __restrict__ flags) {
  alignas(16) __shared__ _Float16 Ah[GM * AKP];   // 10 KB (producer)
  alignas(16) __shared__ _Float16 Bh[GN * AKP];   // 10 KB (producer)
  alignas(16) __shared__ _Float16 Ct[GM * CTP];   // 34 KB (producer)
  alignas(16) __shared__ unsigned char hlds[2][16][HQP];  // 9 KB (consumer)
  alignas(16) __shared__ float hb32[16][H_];      // 16 KB (consumer)

  const int tid = threadIdx.x;
  const int lane = tid & 63;

  if (blockIdx.x >= 4) {
    // ============ PRODUCER (8 waves: 2 m-halves x 4 n-quarters) ============
    const int pidx = blockIdx.x - 4;
    const int bb = pidx / 3;
    const int pp = pidx - bb * 3;
    const int wave = tid >> 6;        // 0..7
    const int ln = lane & 15;
    const int qd = lane >> 4;
    const int wm = (wave & 1) * 64;
    const int wn = (wave >> 1) * 32;  // 0,32,64,96

    for (int mt = 0; mt < 16; mt++) {
      const int m0 = bb * 2048 + mt * 128;
      for (int nh = 0; nh < 2; nh++) {
        const int n0 = pp * 256 + nh * 128;
        f32x4 acc[4][2] = {};
        for (int kc = 0; kc < 10; kc++) {
          const int k0 = kc * 32;
          if (k0 < 64) {
#pragma unroll
            for (int i = 0; i < 2; i++) {
              int idx = tid + i * 512;
              int r = idx >> 3;
              int c4 = (idx & 7) * 4;
              float4 v = *(const float4*)(x + (size_t)(m0 + r) * C_ + k0 + c4);
              h2 lo, hi;
              lo.x = (_Float16)v.x; lo.y = (_Float16)v.y;
              hi.x = (_Float16)v.z; hi.y = (_Float16)v.w;
              h2* d = (h2*)&Ah[r * AKP + c4];
              d[0] = lo; d[1] = hi;
            }
          } else {
#pragma unroll
            for (int i = 0; i < 2; i++) {
              int idx = tid + i * 512;
              int r = idx >> 3;
              int c4 = (idx & 7) * 4;
              uchar4 u = *(const uchar4*)(spk + (size_t)(m0 + r) * H_ + (k0 - 64) + c4);
              h2 lo, hi;
              lo.x = (_Float16)(int)u.x; lo.y = (_Float16)(int)u.y;
              hi.x = (_Float16)(int)u.z; hi.y = (_Float16)(int)u.w;
              h2* d = (h2*)&Ah[r * AKP + c4];
              d[0] = lo; d[1] = hi;
            }
          }
#pragma unroll
          for (int i = 0; i < 2; i++) {
            int idx = tid + i * 512;
            int r = idx >> 3;
            int c4 = (idx & 7) * 4;
            float4 v = *(const float4*)(wih + (size_t)(n0 + r) * 320 + k0 + c4);
            h2 lo, hi;
            lo.x = (_Float16)v.x; lo.y = (_Float16)v.y;
            hi.x = (_Float16)v.z; hi.y = (_Float16)v.w;
            h2* d = (h2*)&Bh[r * AKP + c4];
            d[0] = lo; d[1] = hi;
          }
          __syncthreads();
          {
            f16x8 a[4], bbf[2];
#pragma unroll
            for (int mtl = 0; mtl < 4; mtl++)
              a[mtl] = *(const f16x8*)&Ah[(wm + mtl * 16 + ln) * AKP + qd * 8];
#pragma unroll
            for (int nt = 0; nt < 2; nt++)
              bbf[nt] = *(const f16x8*)&Bh[(wn + nt * 16 + ln) * AKP + qd * 8];
#pragma unroll
            for (int mtl = 0; mtl < 4; mtl++)
#pragma unroll
              for (int nt = 0; nt < 2; nt++)
                acc[mtl][nt] = __builtin_amdgcn_mfma_f32_16x16x32_f16(
                    a[mtl], bbf[nt], acc[mtl][nt], 0, 0, 0);
          }
          __syncthreads();
        }
        {
          float bias[2];
#pragma unroll
          for (int nt = 0; nt < 2; nt++) bias[nt] = bih[n0 + wn + nt * 16 + ln];
#pragma unroll
          for (int mtl = 0; mtl < 4; mtl++)
#pragma unroll
            for (int nt = 0; nt < 2; nt++) {
              int n = wn + nt * 16 + ln;
#pragma unroll
              for (int r = 0; r < 4; r++) {
                int m = wm + mtl * 16 + qd * 4 + r;
                Ct[m * CTP + n] = (_Float16)(acc[mtl][nt][r] + bias[nt]);
              }
            }
        }
        __syncthreads();
#pragma unroll
        for (int i = 0; i < 4; i++) {
          int idx = tid + i * 512;
          int r = idx >> 4;
          int c = (idx & 15) * 8;
          *(h8*)(gx + (size_t)(m0 + r) * G3_ + n0 + c) = *(const h8*)&Ct[r * CTP + c];
        }
        __syncthreads();  // stores drained before flag / Ct reuse
      }
      if (tid == 0)
        __hip_atomic_fetch_add(&flags[bb * 16 + mt], 1, __ATOMIC_RELEASE,
                               __HIP_MEMORY_SCOPE_AGENT);
    }
    return;
  }

  // ========== CONSUMER: 16 batches, MFMA i8 hh-matvec, fp32 tail ==========
  const int b0 = blockIdx.x << 4;   // batches b0..b0+15
  const int w = tid >> 6;           // wave 0..7: owns j-range [w*32, w*32+32)
  const int lb = lane & 15;         // A-row / B-col / D-col (batch)
  const int lk = lane >> 4;         // k-group / D-row-group

  // ---- W fragments: rows {g*256 + w*32 + s*16 + lb}, 4 k-chunks of 64 ----
  i32x4 wf[6][4];   // [g*2+s][chunk] = 96 VGPRs
  {
    const float qs = 2032.0f;  // 127 / 0.0625
#pragma unroll
    for (int g = 0; g < 3; g++)
#pragma unroll
      for (int s = 0; s < 2; s++) {
        const float* row = whh + (size_t)(g * 256 + w * 32 + s * 16 + lb) * H_;
#pragma unroll
        for (int c = 0; c < 4; c++) {
          const int kb = c * 64 + lk * 16;
          i32x4 v;
#pragma unroll
          for (int d = 0; d < 4; d++) {
            float4 f = *(const float4*)(row + kb + d * 4);
            v[d] = ((int)rintf(f.x * qs) & 255) | (((int)rintf(f.y * qs) & 255) << 8) |
                   (((int)rintf(f.z * qs) & 255) << 16) | (((int)rintf(f.w * qs) & 255) << 24);
          }
          wf[g * 2 + s][c] = v;
        }
      }
  }
  // ---- biases for this lane's (j,b) pairs: j = w*32 + s*16 + lk*4 + r ----
  float bR[8], bZ[8], bN[8];
#pragma unroll
  for (int s = 0; s < 2; s++)
#pragma unroll
    for (int r = 0; r < 4; r++) {
      const int jj = w * 32 + s * 16 + lk * 4 + r;
      bR[s * 4 + r] = bhh[jj];
      bZ[s * 4 + r] = bhh[H_ + jj];
      bN[s * 4 + r] = bhh[2 * H_ + jj];
    }
  float ho[8] = {0.f, 0.f, 0.f, 0.f, 0.f, 0.f, 0.f, 0.f};

  for (int i = tid; i < (int)(2 * 16 * HQP / 4); i += 512) ((int*)hlds)[i] = 0;
  __syncthreads();

  // per-lane gx base: batch b0+lb, this wave's j-offset
  const _Float16* gxT = gx + (size_t)(b0 + lb) * T_ * G3_ + w * 32 + lk * 4;
  int p = 0;
  for (int mt = 0; mt < 16; mt++) {
    if (tid < 16) {
      while (__hip_atomic_load(&flags[(b0 + tid) * 16 + mt], __ATOMIC_ACQUIRE,
                               __HIP_MEMORY_SCOPE_AGENT) < 3)
        __builtin_amdgcn_s_sleep(8);
    }
    __syncthreads();

    for (int tt = 0; tt < 128; tt++) {
      // gx for this step: 6 x b64 (4 halves = the 4 D-regs of tile (g,s)).
      // Issued first; MFMA block below covers the L2 latency.
      const _Float16* gp = gxT + (size_t)(mt * 128 + tt) * G3_;
      h4v gv[6];
#pragma unroll
      for (int g = 0; g < 3; g++)
#pragma unroll
        for (int s = 0; s < 2; s++)
          gv[g * 2 + s] = *(const h4v*)(gp + g * 256 + s * 16);

      // h B-fragments: h^T rows (b = lb), k-contiguous
      i32x4 hf[4];
#pragma unroll
      for (int c = 0; c < 4; c++)
        hf[c] = *(const i32x4*)&hlds[p][lb][c * 64 + lk * 16];

      // 24 MFMA: D[j,b] = sum_k W[j,k] h[k,b], exact i32 == sdot4 path
      i32x4 acc[6];
#pragma unroll
      for (int idx = 0; idx < 6; idx++) {
        i32x4 a = {0, 0, 0, 0};
#pragma unroll
        for (int c = 0; c < 4; c++)
          a = __builtin_amdgcn_mfma_i32_16x16x64_i8(wf[idx][c], hf[c], a, 0, 0, 0);
        acc[idx] = a;
      }

      // tail: 8 (j,b) pairs, all gates in-lane (same (row,col) across tiles)
#pragma unroll
      for (int s = 0; s < 2; s++) {
        int packed = 0;
#pragma unroll
        for (int r = 0; r < 4; r++) {
          const float xr = (float)gv[s][r];
          const float xz = (float)gv[2 + s][r];
          const float xn = (float)gv[4 + s][r];
          const float ar = (float)acc[s][r] * DQ_ + bR[s * 4 + r];
          const float az = (float)acc[2 + s][r] * DQ_ + bZ[s * 4 + r];
          const float an = (float)acc[4 + s][r] * DQ_ + bN[s * 4 + r];
          const float rr = 1.f / (1.f + __expf(-(xr + ar)));
          const float zz = 1.f / (1.f + __expf(-(xz + az)));
          const float pre = xn + rr * an;
          const float e = __expf(2.f * pre);   // tanh = 1 - 2/(e^{2x}+1)
          const float nn = 1.f - 2.f / (e + 1.f);
          const float h = (1.f - zz) * nn + zz * ho[s * 4 + r];
          ho[s * 4 + r] = h;
          packed |= ((int)rintf(h * 127.0f) & 255) << (8 * r);
        }
        *(int*)&hlds[p ^ 1][lb][w * 32 + s * 16 + lk * 4] = packed;
      }
      p ^= 1;
      __syncthreads();   // the ONLY barrier per step
    }
  }

  // ---- head: hT [16 x 256] -> out [16 x 96] ----
#pragma unroll
  for (int s = 0; s < 2; s++)
#pragma unroll
    for (int r = 0; r < 4; r++)
      hb32[lb][w * 32 + s * 16 + lk * 4 + r] = ho[s * 4 + r];
  __syncthreads();

#pragma unroll
  for (int i = 0; i < 3; i++) {
    const int o = tid + i * 512;          // 0..1535
    const int bb2 = o / 96, rr2 = o % 96;
    const float4* hw = (const float4*)(head_w + (size_t)rr2 * H_);
    const float4* hv = (const float4*)&hb32[bb2][0];
    float acc2 = head_b[rr2];
#pragma unroll
    for (int q = 0; q < H_ / 4; q++) {
      float4 w4 = hw[q];
      float4 v4 = hv[q];
      acc2 += w4.x * v4.x + w4.y * v4.y + w4.z * v4.z + w4.w * v4.w;
    }
    out[(size_t)(b0 + bb2) * HOR_ + rr2] = acc2;
  }
}

// ---------------------------------------------------------------------------
extern "C" void kernel_launch(void* const* d_in, const int* in_sizes, int n_in,
                              void* d_out, int out_size, void* d_ws, size_t ws_size,
                              hipStream_t stream) {
  const float* x      = (const float*)d_in[0];
  const float* snn_w  = (const float*)d_in[1];
  const float* snn_b  = (const float*)d_in[2];
  const float* wih    = (const float*)d_in[3];
  const float* whh    = (const float*)d_in[4];
  const float* bih    = (const float*)d_in[5];
  const float* bhh    = (const float*)d_in[6];
  const float* head_w = (const float*)d_in[7];
  const float* head_b = (const float*)d_in[8];
  float* out = (float*)d_out;

  // ws layout (235 MB + 4 KB flags):
  //   [0, 201326592)          gx fp16 [131072,768]
  //   [0, 134217728)          cur fp32 [131072,256] — alias, dead before fused
  //   [201326592, 234881024)  spk u8 [131072,256]
  //   [234881024, 234885120)  flags int[1024]
  char* ws = (char*)d_ws;
  _Float16* gx = (_Float16*)ws;
  float* cur = (float*)ws;
  unsigned char* spk = (unsigned char*)(ws + (size_t)201326592);
  int* flags = (int*)(ws + (size_t)234881024);

  k_cur<<<dim3(B_, T_ / K1_TT), 256, 0, stream>>>(x, snn_w, snn_b, cur, flags);
  k_lif<<<dim3(256), 64, 0, stream>>>(cur, spk);
  k_fused<<<dim3(196), 512, 0, stream>>>(x, spk, wih, bih, gx, whh, bhh,
                                         head_w, head_b, out, flags);
}